// Round 3
// baseline (45.352 us; speedup 1.0000x reference)
//
#include <hip/hip_runtime.h>
#include <math.h>

// Chamfer loss, B=8, C=3, M=N=4096, fp32.
// diff[b,m,n] = ||src[b,:,m] - dst[b,:,n]||_2
// out = mean_bm(min_n diff) + mean_bn(min_m diff)   (3 identical scalars)
//
// min commutes with sqrt(max(.,0)) -> track min squared distance.
// d^2 = ||p||^2 + 2*(||r||^2/2 - p.r)  -> inner loop = 3 FMA + 0.5 min3 per pair
// (h = ||r||^2/2 precomputed at LDS-staging time; query coords pre-negated).
//
// MPT=16: each ds_read_b128 broadcast is reused by 16 query points ->
// LDS pipe at ~43% of VALU load (was ~86% at MPT=8).

constexpr int B      = 8;
constexpr int M      = 4096;
constexpr int N      = 4096;
constexpr int BLOCK  = 256;
constexpr int MPT    = 16;              // query points per thread
constexpr int PPB    = BLOCK * MPT;     // 4096 = M: every block covers all queries
constexpr int NSPLIT = 64;              // split of the reference-point loop
constexpr int NCHUNK = N / NSPLIT;      // 64 reference points staged in LDS

// ws: uint-punned float min-sq-dist, [2][B][4096] (256 KB)

__global__ __launch_bounds__(BLOCK, 4) void chamfer_min_kernel(
    const float* __restrict__ src,
    const float* __restrict__ dst,
    unsigned int* __restrict__ wsmin)
{
    int bid = blockIdx.x;
    const int nc  = bid % NSPLIT; bid /= NSPLIT;
    const int b   = bid % B;      bid /= B;
    const int dir = bid;          // 0: query=src scan dst, 1: query=dst scan src

    const float* __restrict__ qry = dir ? dst : src;
    const float* __restrict__ ref = dir ? src : dst;

    __shared__ __align__(16) float rx[NCHUNK];
    __shared__ __align__(16) float ry[NCHUNK];
    __shared__ __align__(16) float rz[NCHUNK];
    __shared__ __align__(16) float rh[NCHUNK];   // ||r||^2 / 2

    const float* refb = ref + (size_t)b * 3 * N + nc * NCHUNK;
    for (int i = threadIdx.x; i < NCHUNK; i += BLOCK) {
        const float x = refb[0 * N + i];
        const float y = refb[1 * N + i];
        const float z = refb[2 * N + i];
        rx[i] = x; ry[i] = y; rz[i] = z;
        rh[i] = 0.5f * (x * x + y * y + z * z);
    }
    __syncthreads();

    const float* qb = qry + (size_t)b * 3 * M;
    const int p0 = threadIdx.x;

    float npx[MPT], npy[MPT], npz[MPT], p2[MPT];
#pragma unroll
    for (int t = 0; t < MPT; ++t) {
        const int p = p0 + t * BLOCK;
        const float x = qb[0 * M + p];
        const float y = qb[1 * M + p];
        const float z = qb[2 * M + p];
        npx[t] = -x; npy[t] = -y; npz[t] = -z;
        p2[t] = x * x + y * y + z * z;
    }

    float mn[MPT];
#pragma unroll
    for (int t = 0; t < MPT; ++t) mn[t] = 3.0e38f;

#pragma unroll 4
    for (int j = 0; j < NCHUNK; j += 4) {
        const float4 vx = *reinterpret_cast<const float4*>(&rx[j]);
        const float4 vy = *reinterpret_cast<const float4*>(&ry[j]);
        const float4 vz = *reinterpret_cast<const float4*>(&rz[j]);
        const float4 vh = *reinterpret_cast<const float4*>(&rh[j]);
#pragma unroll
        for (int t = 0; t < MPT; ++t) {
            float q0, q1, q2, q3;
            q0 = fmaf(npx[t], vx.x, vh.x);
            q0 = fmaf(npy[t], vy.x, q0);
            q0 = fmaf(npz[t], vz.x, q0);
            q1 = fmaf(npx[t], vx.y, vh.y);
            q1 = fmaf(npy[t], vy.y, q1);
            q1 = fmaf(npz[t], vz.y, q1);
            mn[t] = fminf(mn[t], fminf(q0, q1));      // -> v_min3_f32
            q2 = fmaf(npx[t], vx.z, vh.z);
            q2 = fmaf(npy[t], vy.z, q2);
            q2 = fmaf(npz[t], vz.z, q2);
            q3 = fmaf(npx[t], vx.w, vh.w);
            q3 = fmaf(npy[t], vy.w, q3);
            q3 = fmaf(npz[t], vz.w, q3);
            mn[t] = fminf(mn[t], fminf(q2, q3));      // -> v_min3_f32
        }
    }

    unsigned int* wm = wsmin + ((size_t)dir * B + b) * M;
#pragma unroll
    for (int t = 0; t < MPT; ++t) {
        // d^2 = p2 + 2*min_q; clamp at 0 so uint-punned compare stays valid
        const float s = fmaxf(fmaf(2.0f, mn[t], p2[t]), 0.0f);
        atomicMin(&wm[p0 + t * BLOCK], __float_as_uint(s));
    }
}

__global__ __launch_bounds__(256) void chamfer_reduce_kernel(
    const unsigned int* __restrict__ wsmin, float* __restrict__ out)
{
    const int idx = blockIdx.x * 256 + threadIdx.x;   // grid covers 2*B*M exactly
    const float v = __uint_as_float(wsmin[idx]);
    float s = sqrtf(fmaxf(v, 0.0f)) * (1.0f / (float)(B * M));
    // fwd mean /(B*M), bwd /(B*N); M==N -> total = sum(all)/(B*M)
#pragma unroll
    for (int off = 32; off > 0; off >>= 1) s += __shfl_down(s, off);
    __shared__ float partial[4];
    const int wave = threadIdx.x >> 6;
    if ((threadIdx.x & 63) == 0) partial[wave] = s;
    __syncthreads();
    if (threadIdx.x == 0) {
        const float tot = partial[0] + partial[1] + partial[2] + partial[3];
        atomicAdd(&out[0], tot);
        atomicAdd(&out[1], tot);
        atomicAdd(&out[2], tot);
    }
}

extern "C" void kernel_launch(void* const* d_in, const int* in_sizes, int n_in,
                              void* d_out, int out_size, void* d_ws, size_t ws_size,
                              hipStream_t stream)
{
    const float* src = (const float*)d_in[0];   // [B,3,M]
    const float* dst = (const float*)d_in[1];   // [B,3,N]
    float* out = (float*)d_out;                 // 3 floats
    unsigned int* wsmin = (unsigned int*)d_ws;  // [2][B][4096]

    const size_t wsbytes = (size_t)2 * B * M * sizeof(unsigned int);  // 256 KB
    hipMemsetAsync(d_ws, 0x7f, wsbytes, stream);    // 0x7f7f7f7f ~ 3.39e38f
    hipMemsetAsync(d_out, 0, (size_t)out_size * sizeof(float), stream);

    const int nblocks = 2 * B * NSPLIT;              // 1024
    chamfer_min_kernel<<<nblocks, BLOCK, 0, stream>>>(src, dst, wsmin);

    const int rblocks = 2 * B * M / 256;             // 256
    chamfer_reduce_kernel<<<rblocks, 256, 0, stream>>>(wsmin, out);
}

// Round 4
// 45.135 us; speedup vs baseline: 1.0048x; 1.0048x over previous
//
#include <hip/hip_runtime.h>
#include <math.h>

// Chamfer loss, B=8, C=3, M=N=4096, fp32.
// diff[b,m,n] = ||src[b,:,m] - dst[b,:,n]||_2
// out = mean_bm(min_n diff) + mean_bn(min_m diff)   (3 identical scalars)
//
// min commutes with sqrt(max(.,0)) -> track min squared distance.
// d^2 = ||p||^2 + 2*(||r||^2/2 - p.r)  -> inner loop = 3 FMA + 0.5 min3 per pair.
//
// Round-4 structure: NO global atomics in the hot kernel (atomics were
// memory-side RMWs costing ~10 us at 2M+ ops). Each block plain-stores its
// partial min-d^2 for its (dir,b,nc) slice into a disjoint ws slot; a second
// pass min-reduces over nc, takes sqrt, and accumulates the mean.

constexpr int B      = 8;
constexpr int M      = 4096;
constexpr int N      = 4096;
constexpr int BLOCK  = 256;
constexpr int MPT    = 8;               // query points per thread
constexpr int PPB    = BLOCK * MPT;     // 2048 query points per block
constexpr int NSPLIT = 32;              // split of the reference-point loop
constexpr int NCHUNK = N / NSPLIT;      // 128 reference points staged in LDS

// ws: float partial min-sq-dist, part[2][B][NSPLIT][4096]  (8 MB of 256 MB ws)

__global__ __launch_bounds__(BLOCK) void chamfer_min_kernel(
    const float* __restrict__ src,
    const float* __restrict__ dst,
    float* __restrict__ part)
{
    int bid = blockIdx.x;
    const int nc  = bid % NSPLIT;    bid /= NSPLIT;
    const int pc  = bid % (M / PPB); bid /= (M / PPB);
    const int b   = bid % B;         bid /= B;
    const int dir = bid;             // 0: query=src scan dst, 1: query=dst scan src

    const float* __restrict__ qry = dir ? dst : src;
    const float* __restrict__ ref = dir ? src : dst;

    __shared__ __align__(16) float rx[NCHUNK];
    __shared__ __align__(16) float ry[NCHUNK];
    __shared__ __align__(16) float rz[NCHUNK];
    __shared__ __align__(16) float rh[NCHUNK];   // ||r||^2 / 2

    const float* refb = ref + (size_t)b * 3 * N + nc * NCHUNK;
    for (int i = threadIdx.x; i < NCHUNK; i += BLOCK) {
        const float x = refb[0 * N + i];
        const float y = refb[1 * N + i];
        const float z = refb[2 * N + i];
        rx[i] = x; ry[i] = y; rz[i] = z;
        rh[i] = 0.5f * (x * x + y * y + z * z);
    }
    __syncthreads();

    const float* qb = qry + (size_t)b * 3 * M;
    const int p0 = pc * PPB + threadIdx.x;

    float npx[MPT], npy[MPT], npz[MPT], p2[MPT];
#pragma unroll
    for (int t = 0; t < MPT; ++t) {
        const int p = p0 + t * BLOCK;
        const float x = qb[0 * M + p];
        const float y = qb[1 * M + p];
        const float z = qb[2 * M + p];
        npx[t] = -x; npy[t] = -y; npz[t] = -z;
        p2[t] = x * x + y * y + z * z;
    }

    float mn[MPT];
#pragma unroll
    for (int t = 0; t < MPT; ++t) mn[t] = 3.0e38f;

#pragma unroll 4
    for (int j = 0; j < NCHUNK; j += 4) {
        const float4 vx = *reinterpret_cast<const float4*>(&rx[j]);
        const float4 vy = *reinterpret_cast<const float4*>(&ry[j]);
        const float4 vz = *reinterpret_cast<const float4*>(&rz[j]);
        const float4 vh = *reinterpret_cast<const float4*>(&rh[j]);
#pragma unroll
        for (int t = 0; t < MPT; ++t) {
            float q0, q1, q2, q3;
            q0 = fmaf(npx[t], vx.x, vh.x);
            q0 = fmaf(npy[t], vy.x, q0);
            q0 = fmaf(npz[t], vz.x, q0);
            q1 = fmaf(npx[t], vx.y, vh.y);
            q1 = fmaf(npy[t], vy.y, q1);
            q1 = fmaf(npz[t], vz.y, q1);
            mn[t] = fminf(mn[t], fminf(q0, q1));      // -> v_min3_f32
            q2 = fmaf(npx[t], vx.z, vh.z);
            q2 = fmaf(npy[t], vy.z, q2);
            q2 = fmaf(npz[t], vz.z, q2);
            q3 = fmaf(npx[t], vx.w, vh.w);
            q3 = fmaf(npy[t], vy.w, q3);
            q3 = fmaf(npz[t], vz.w, q3);
            mn[t] = fminf(mn[t], fminf(q2, q3));      // -> v_min3_f32
        }
    }

    // plain disjoint stores: part[((dir*B + b)*NSPLIT + nc)*M + q]
    float* wm = part + (((size_t)dir * B + b) * NSPLIT + nc) * M;
#pragma unroll
    for (int t = 0; t < MPT; ++t) {
        // partial min of d^2 = p2 + 2*min_q (may be slightly negative; pass 2 clamps)
        wm[p0 + t * BLOCK] = fmaf(2.0f, mn[t], p2[t]);
    }
}

__global__ __launch_bounds__(256) void chamfer_reduce_kernel(
    const float* __restrict__ part, float* __restrict__ out)
{
    const int idx = blockIdx.x * 256 + threadIdx.x;   // grid covers 2*B*M exactly
    const int q  = idx & (M - 1);
    const int db = idx >> 12;                         // dir*B + b

    // 4 independent min chains over the NSPLIT partials (coalesced on q)
    const float* p = part + (size_t)db * NSPLIT * M + q;
    float m0 = 3.0e38f, m1 = 3.0e38f, m2 = 3.0e38f, m3 = 3.0e38f;
#pragma unroll
    for (int nc = 0; nc < NSPLIT; nc += 4) {
        m0 = fminf(m0, p[(nc + 0) * M]);
        m1 = fminf(m1, p[(nc + 1) * M]);
        m2 = fminf(m2, p[(nc + 2) * M]);
        m3 = fminf(m3, p[(nc + 3) * M]);
    }
    const float v = fminf(fminf(m0, m1), fminf(m2, m3));

    float s = sqrtf(fmaxf(v, 0.0f)) * (1.0f / (float)(B * M));
    // fwd mean /(B*M), bwd /(B*N); M==N -> total = sum(all)/(B*M)
#pragma unroll
    for (int off = 32; off > 0; off >>= 1) s += __shfl_down(s, off);
    __shared__ float partial[4];
    const int wave = threadIdx.x >> 6;
    if ((threadIdx.x & 63) == 0) partial[wave] = s;
    __syncthreads();
    if (threadIdx.x == 0) {
        const float tot = partial[0] + partial[1] + partial[2] + partial[3];
        atomicAdd(&out[0], tot);
        atomicAdd(&out[1], tot);
        atomicAdd(&out[2], tot);
    }
}

extern "C" void kernel_launch(void* const* d_in, const int* in_sizes, int n_in,
                              void* d_out, int out_size, void* d_ws, size_t ws_size,
                              hipStream_t stream)
{
    const float* src = (const float*)d_in[0];   // [B,3,M]
    const float* dst = (const float*)d_in[1];   // [B,3,N]
    float* out = (float*)d_out;                 // 3 floats
    float* part = (float*)d_ws;                 // [2][B][NSPLIT][4096] = 8 MB

    hipMemsetAsync(d_out, 0, (size_t)out_size * sizeof(float), stream);

    const int nblocks = 2 * B * (M / PPB) * NSPLIT;  // 1024
    chamfer_min_kernel<<<nblocks, BLOCK, 0, stream>>>(src, dst, part);

    const int rblocks = 2 * B * M / 256;             // 256
    chamfer_reduce_kernel<<<rblocks, 256, 0, stream>>>(part, out);
}

// Round 5
// 42.567 us; speedup vs baseline: 1.0654x; 1.0603x over previous
//
#include <hip/hip_runtime.h>
#include <math.h>

// Chamfer loss, B=8, C=3, M=N=4096, fp32 — MFMA formulation.
//
// sq[m][n] = s2[m] + d2[n] - 2 s.d  is a K=16 GEMM with augmented bf16 hi/lo
// split vectors (error ~2^-18 per product, ~1e-4 on d — threshold is 6.3e-3):
//   A_m = [-2hx,-2hx,-2lx,-2lx | y... | z... | s2h,s2l, 1,1]
//   B_n = [ hx,  lx,  hx,  lx  | y... | z... | 1,1, d2h,d2l]
// One v_mfma_f32_32x32x16_bf16 per 32x32 tile puts sq straight into the
// accumulator; fwd (min over n) and bwd (min over m) both reduce from the
// SAME tile -> one pass over 134M pairs instead of two scalar passes.
//
// C layout (m74/m101): col = lane&31, row = (reg&3) + 8*(reg>>2) + 4*(lane>>5)
// A frag: row = lane&31, k = (lane>>5)*8 + j ; B frag: col = lane&31, same k.

constexpr int B = 8;
constexpr int M = 4096;
constexpr int N = 4096;

typedef __attribute__((ext_vector_type(8)))  short bf16x8;
typedef __attribute__((ext_vector_type(16))) float f32x16;

__device__ inline unsigned short bf16_of(float x) {   // round-to-nearest-even
    unsigned int u = __float_as_uint(x);
    u += 0x7FFFu + ((u >> 16) & 1u);
    return (unsigned short)(u >> 16);
}
__device__ inline float bf16_to_f(unsigned short h) {
    return __uint_as_float(((unsigned int)h) << 16);
}

// ws layout (bytes):  Aaug [B][2][M][8]bf16 @ 0       (1 MB)
//                     Baug [B][2][N][8]bf16 @ 1 MB    (1 MB)
//                     part_fwd [8][B][M]f32 @ 2 MB    (1 MB)
//                     part_bwd [32][B][N]f32 @ 4 MB   (4 MB)

__global__ __launch_bounds__(256) void chamfer_pre(
    const float* __restrict__ src, const float* __restrict__ dst,
    unsigned short* __restrict__ Aaug, unsigned short* __restrict__ Baug)
{
    int idx = blockIdx.x * 256 + threadIdx.x;          // [0, 2*B*M)
    const int i     = idx & (M - 1); idx >>= 12;
    const int b     = idx & (B - 1); idx >>= 3;
    const int which = idx;                             // 0 = src(A), 1 = dst(B)

    const float* in = which ? dst : src;
    const float x = in[((size_t)b * 3 + 0) * M + i];
    const float y = in[((size_t)b * 3 + 1) * M + i];
    const float z = in[((size_t)b * 3 + 2) * M + i];
    const float s2 = x * x + y * y + z * z;

    const unsigned short xh = bf16_of(x); const float xhf = bf16_to_f(xh);
    const unsigned short yh = bf16_of(y); const float yhf = bf16_to_f(yh);
    const unsigned short zh = bf16_of(z); const float zhf = bf16_to_f(zh);
    const unsigned short s2h = bf16_of(s2); const float s2hf = bf16_to_f(s2h);
    const unsigned short s2l = bf16_of(s2 - s2hf);
    const unsigned short one = 0x3F80;

    __align__(16) unsigned short v[16];
    unsigned short* outp;
    if (which == 0) {
        // A: -2*hi is exact (power-of-2 scale of a bf16 value)
        const unsigned short nxh = bf16_of(-2.0f * xhf), nxl = bf16_of(-2.0f * (x - xhf));
        const unsigned short nyh = bf16_of(-2.0f * yhf), nyl = bf16_of(-2.0f * (y - yhf));
        const unsigned short nzh = bf16_of(-2.0f * zhf), nzl = bf16_of(-2.0f * (z - zhf));
        v[0]=nxh; v[1]=nxh; v[2]=nxl; v[3]=nxl;
        v[4]=nyh; v[5]=nyh; v[6]=nyl; v[7]=nyl;
        v[8]=nzh; v[9]=nzh; v[10]=nzl; v[11]=nzl;
        v[12]=s2h; v[13]=s2l; v[14]=one; v[15]=one;
        outp = Aaug;
    } else {
        const unsigned short xl = bf16_of(x - xhf);
        const unsigned short yl = bf16_of(y - yhf);
        const unsigned short zl = bf16_of(z - zhf);
        v[0]=xh; v[1]=xl; v[2]=xh; v[3]=xl;
        v[4]=yh; v[5]=yl; v[6]=yh; v[7]=yl;
        v[8]=zh; v[9]=zl; v[10]=zh; v[11]=zl;
        v[12]=one; v[13]=one; v[14]=s2h; v[15]=s2l;
        outp = Baug;
    }
#pragma unroll
    for (int kg = 0; kg < 2; ++kg)
        *reinterpret_cast<bf16x8*>(&outp[(((size_t)b * 2 + kg) * M + i) * 8]) =
            *reinterpret_cast<const bf16x8*>(&v[kg * 8]);
}

// grid 2048 = (b, mg in [0,32), ns in [0,8)); 4 waves, wave w owns m-tile mg*4+w
__global__ __launch_bounds__(256) void chamfer_mfma(
    const unsigned short* __restrict__ Aaug,
    const unsigned short* __restrict__ Baug,
    float* __restrict__ part_fwd,     // [8][B][M]
    float* __restrict__ part_bwd)     // [32][B][N]
{
    int bid = blockIdx.x;
    const int ns = bid & 7;  bid >>= 3;
    const int mg = bid & 31; bid >>= 5;
    const int b  = bid;

    const int tid  = threadIdx.x;
    const int wave = tid >> 6;
    const int lane = tid & 63;
    const int l31  = lane & 31;
    const int hf   = lane >> 5;     // k-group / row-half

    __shared__ __align__(16) unsigned short bstage[2][512][8];  // 16 KB
    __shared__ unsigned int bwd_lds[512];                       // 2 KB

    // stage B fragments for cols [ns*512, ns*512+512): chunk c = kg*512 + row
    for (int c = tid; c < 1024; c += 256) {
        const int kg = c >> 9, row = c & 511;
        *reinterpret_cast<bf16x8*>(&bstage[kg][row][0]) =
            *reinterpret_cast<const bf16x8*>(
                &Baug[(((size_t)b * 2 + kg) * N + ns * 512 + row) * 8]);
    }
    bwd_lds[tid]       = 0x7f7fffffu;   // FLT_MAX
    bwd_lds[tid + 256] = 0x7f7fffffu;

    // A fragment — constant across the n loop
    const int mrow = mg * 128 + wave * 32 + l31;
    const bf16x8 afrag = *reinterpret_cast<const bf16x8*>(
        &Aaug[(((size_t)b * 2 + hf) * M + mrow) * 8]);

    __syncthreads();

    f32x16 fwd;
#pragma unroll
    for (int r = 0; r < 16; ++r) fwd[r] = 3.0e38f;

    const f32x16 zero = {};   // C-operand = 0: acc receives sq directly

#pragma unroll 2
    for (int nt = 0; nt < 16; ++nt) {
        const bf16x8 bfrag = *reinterpret_cast<const bf16x8*>(
            &bstage[hf][nt * 32 + l31][0]);
        f32x16 acc = __builtin_amdgcn_mfma_f32_32x32x16_bf16(afrag, bfrag, zero, 0, 0, 0);

        // fwd: running per-element min (row m fixed per (reg,half), col varies per tile)
#pragma unroll
        for (int r = 0; r < 16; ++r) fwd[r] = fminf(fwd[r], acc[r]);

        // bwd: min over this lane's 16 rows of col = nbase + l31, then LDS-merge
        float c0 = fminf(fminf(acc[0],  acc[1]),  fminf(acc[2],  acc[3]));
        float c1 = fminf(fminf(acc[4],  acc[5]),  fminf(acc[6],  acc[7]));
        float c2 = fminf(fminf(acc[8],  acc[9]),  fminf(acc[10], acc[11]));
        float c3 = fminf(fminf(acc[12], acc[13]), fminf(acc[14], acc[15]));
        float cm = fmaxf(fminf(fminf(c0, c1), fminf(c2, c3)), 0.0f);
        atomicMin(&bwd_lds[nt * 32 + l31], __float_as_uint(cm));  // both halves merge
    }

    // fwd: butterfly min across the 32-lane col dimension, then 2 lanes store
#pragma unroll
    for (int r = 0; r < 16; ++r) {
        float vv = fwd[r];
        vv = fminf(vv, __shfl_xor(vv, 1));
        vv = fminf(vv, __shfl_xor(vv, 2));
        vv = fminf(vv, __shfl_xor(vv, 4));
        vv = fminf(vv, __shfl_xor(vv, 8));
        vv = fminf(vv, __shfl_xor(vv, 16));
        fwd[r] = vv;
    }
    if (l31 == 0) {   // lanes 0 (rows h=0) and 32 (rows h=1)
        float* pf = part_fwd + (((size_t)ns * B) + b) * M + mg * 128 + wave * 32 + hf * 4;
#pragma unroll
        for (int r = 0; r < 16; ++r)
            pf[(r & 3) + 8 * (r >> 2)] = fwd[r];
    }

    __syncthreads();
    {
        float* pb = part_bwd + (((size_t)mg * B) + b) * N + ns * 512;
        pb[tid]       = __uint_as_float(bwd_lds[tid]);
        pb[tid + 256] = __uint_as_float(bwd_lds[tid + 256]);
    }
}

__global__ __launch_bounds__(256) void chamfer_reduce(
    const float* __restrict__ part_fwd, const float* __restrict__ part_bwd,
    float* __restrict__ out)
{
    int idx = blockIdx.x * 256 + threadIdx.x;   // [0, 2*B*M); dir uniform per block
    const int q   = idx & (M - 1); idx >>= 12;
    const int b   = idx & (B - 1); idx >>= 3;
    const int dir = idx;

    float m0 = 3.0e38f, m1 = 3.0e38f, m2 = 3.0e38f, m3 = 3.0e38f;
    if (dir == 0) {
        const float* p = part_fwd + (size_t)b * M + q;
#pragma unroll
        for (int k = 0; k < 8; k += 4) {
            m0 = fminf(m0, p[(size_t)(k + 0) * B * M]);
            m1 = fminf(m1, p[(size_t)(k + 1) * B * M]);
            m2 = fminf(m2, p[(size_t)(k + 2) * B * M]);
            m3 = fminf(m3, p[(size_t)(k + 3) * B * M]);
        }
    } else {
        const float* p = part_bwd + (size_t)b * N + q;
#pragma unroll
        for (int k = 0; k < 32; k += 4) {
            m0 = fminf(m0, p[(size_t)(k + 0) * B * N]);
            m1 = fminf(m1, p[(size_t)(k + 1) * B * N]);
            m2 = fminf(m2, p[(size_t)(k + 2) * B * N]);
            m3 = fminf(m3, p[(size_t)(k + 3) * B * N]);
        }
    }
    const float v = fminf(fminf(m0, m1), fminf(m2, m3));

    float s = sqrtf(fmaxf(v, 0.0f)) * (1.0f / (float)(B * M));  // M==N: one scale
#pragma unroll
    for (int off = 32; off > 0; off >>= 1) s += __shfl_down(s, off);
    __shared__ float partial[4];
    if ((threadIdx.x & 63) == 0) partial[threadIdx.x >> 6] = s;
    __syncthreads();
    if (threadIdx.x == 0) {
        const float tot = partial[0] + partial[1] + partial[2] + partial[3];
        atomicAdd(&out[0], tot);
        atomicAdd(&out[1], tot);
        atomicAdd(&out[2], tot);
    }
}

extern "C" void kernel_launch(void* const* d_in, const int* in_sizes, int n_in,
                              void* d_out, int out_size, void* d_ws, size_t ws_size,
                              hipStream_t stream)
{
    const float* src = (const float*)d_in[0];   // [B,3,M]
    const float* dst = (const float*)d_in[1];   // [B,3,N]
    float* out = (float*)d_out;

    unsigned short* Aaug = (unsigned short*)d_ws;
    unsigned short* Baug = (unsigned short*)((char*)d_ws + (1u << 20));
    float* pfwd = (float*)((char*)d_ws + (2u << 20));
    float* pbwd = (float*)((char*)d_ws + (4u << 20));

    hipMemsetAsync(d_out, 0, (size_t)out_size * sizeof(float), stream);

    chamfer_pre<<<2 * B * M / 256, 256, 0, stream>>>(src, dst, Aaug, Baug);
    chamfer_mfma<<<B * 32 * 8, 256, 0, stream>>>(Aaug, Baug, pfwd, pbwd);
    chamfer_reduce<<<2 * B * M / 256, 256, 0, stream>>>(pfwd, pbwd, out);
}

// Round 6
// 41.308 us; speedup vs baseline: 1.0979x; 1.0305x over previous
//
#include <hip/hip_runtime.h>
#include <math.h>

// Chamfer loss, B=8, C=3, M=N=4096, fp32 — fused MFMA formulation.
//
// sq[m][n] = s2[m] + d2[n] - 2 s.d as a K=16 bf16 GEMM with hi/lo split
// (abs err ~1e-5 on sq; threshold 6.3e-3 on the mean of d):
//   A_m = [-2xh,-2xh,-2xl,-2xl | y.. | z.. | s2h,s2l,1,1]
//   B_n = [ xh,  xl,  xh,  xl  | y.. | z.. | 1,1,d2h,d2l]
// One v_mfma_f32_32x32x16_bf16 per 32x32 tile -> sq in the accumulator.
// fwd (min over n) and bwd (min over m) both reduce from the same tile:
// one pass over 134M pairs. Augmentation is built IN-kernel (no pre pass).
//
// C layout (m74/m101): col = lane&31, row = (reg&3) + 8*(reg>>2) + 4*(lane>>5)
// A frag: row = lane&31, k = (lane>>5)*8 + j ; B frag: col = lane&31, same k.

constexpr int B = 8;
constexpr int M = 4096;
constexpr int N = 4096;

typedef __attribute__((ext_vector_type(8)))  short bf16x8;
typedef __attribute__((ext_vector_type(16))) float f32x16;

__device__ inline unsigned short bf16_of(float x) {   // round-to-nearest-even
    unsigned int u = __float_as_uint(x);
    u += 0x7FFFu + ((u >> 16) & 1u);
    return (unsigned short)(u >> 16);
}
__device__ inline float bf16_to_f(unsigned short h) {
    return __uint_as_float(((unsigned int)h) << 16);
}

// ws: part_fwd [8][B][M] f32 @ 0      (1 MB)
//     part_bwd [32][B][N] f32 @ 4 MB  (4 MB)

// grid 2048 = (b<<8 | mg<<3 | ns); 4 waves, wave w owns m-tile mg*128+w*32
__global__ __launch_bounds__(256) void chamfer_mfma(
    const float* __restrict__ src,
    const float* __restrict__ dst,
    float* __restrict__ part_fwd,     // [8][B][M]
    float* __restrict__ part_bwd)     // [32][B][N]
{
    int bid = blockIdx.x;
    const int ns = bid & 7;  bid >>= 3;
    const int mg = bid & 31; bid >>= 5;
    const int b  = bid;

    const int tid  = threadIdx.x;
    const int wave = tid >> 6;
    const int lane = tid & 63;
    const int l31  = lane & 31;
    const int hf   = lane >> 5;     // k-group / row-half

    __shared__ __align__(16) unsigned short bstage[2][512][8];  // 16 KB
    __shared__ unsigned int bwd_lds[512];                       // 2 KB

    // ---- stage augmented B fragments for cols [ns*512, ns*512+512) ----
    const float* db = dst + (size_t)b * 3 * N + ns * 512;
    for (int col = tid; col < 512; col += 256) {
        const float x = db[0 * N + col];
        const float y = db[1 * N + col];
        const float z = db[2 * N + col];
        const float d2 = x * x + y * y + z * z;
        const unsigned short xh = bf16_of(x); const unsigned short xl = bf16_of(x - bf16_to_f(xh));
        const unsigned short yh = bf16_of(y); const unsigned short yl = bf16_of(y - bf16_to_f(yh));
        const unsigned short zh = bf16_of(z); const unsigned short zl = bf16_of(z - bf16_to_f(zh));
        const unsigned short d2h = bf16_of(d2);
        const unsigned short d2l = bf16_of(d2 - bf16_to_f(d2h));
        const unsigned short one = 0x3F80;
        bf16x8 v0, v1;
        v0[0]=(short)xh; v0[1]=(short)xl; v0[2]=(short)xh; v0[3]=(short)xl;
        v0[4]=(short)yh; v0[5]=(short)yl; v0[6]=(short)yh; v0[7]=(short)yl;
        v1[0]=(short)zh; v1[1]=(short)zl; v1[2]=(short)zh; v1[3]=(short)zl;
        v1[4]=(short)one; v1[5]=(short)one; v1[6]=(short)d2h; v1[7]=(short)d2l;
        *reinterpret_cast<bf16x8*>(&bstage[0][col][0]) = v0;
        *reinterpret_cast<bf16x8*>(&bstage[1][col][0]) = v1;
    }
    bwd_lds[tid]       = 0x7f7fffffu;   // FLT_MAX bits
    bwd_lds[tid + 256] = 0x7f7fffffu;

    // ---- build augmented A fragment for this lane's row (constant in loop) ----
    const int mrow = mg * 128 + wave * 32 + l31;
    bf16x8 afrag;
    {
        const float* sb = src + (size_t)b * 3 * M;
        const float x = sb[0 * M + mrow];
        const float y = sb[1 * M + mrow];
        const float z = sb[2 * M + mrow];
        const float s2 = x * x + y * y + z * z;
        const float xhf = bf16_to_f(bf16_of(x));
        const float yhf = bf16_to_f(bf16_of(y));
        const float zhf = bf16_to_f(bf16_of(z));
        // -2*hi exact (pow2 scale of bf16 value)
        const unsigned short nxh = bf16_of(-2.0f * xhf), nxl = bf16_of(-2.0f * (x - xhf));
        const unsigned short nyh = bf16_of(-2.0f * yhf), nyl = bf16_of(-2.0f * (y - yhf));
        const unsigned short nzh = bf16_of(-2.0f * zhf), nzl = bf16_of(-2.0f * (z - zhf));
        const unsigned short s2h = bf16_of(s2);
        const unsigned short s2l = bf16_of(s2 - bf16_to_f(s2h));
        const unsigned short one = 0x3F80;
        bf16x8 alo, ahi;
        alo[0]=(short)nxh; alo[1]=(short)nxh; alo[2]=(short)nxl; alo[3]=(short)nxl;
        alo[4]=(short)nyh; alo[5]=(short)nyh; alo[6]=(short)nyl; alo[7]=(short)nyl;
        ahi[0]=(short)nzh; ahi[1]=(short)nzh; ahi[2]=(short)nzl; ahi[3]=(short)nzl;
        ahi[4]=(short)s2h; ahi[5]=(short)s2l; ahi[6]=(short)one; ahi[7]=(short)one;
        afrag = hf ? ahi : alo;
    }

    __syncthreads();

    f32x16 fwd;
#pragma unroll
    for (int r = 0; r < 16; ++r) fwd[r] = 3.0e38f;

    const f32x16 zero = {};

    // 2 tiles per step; wave-staggered nt order de-conflicts the LDS atomics
#pragma unroll
    for (int i = 0; i < 8; ++i) {
        const int nt = (i * 2 + wave * 4) & 15;     // even; nt+1 <= 15
        const bf16x8 bf0 = *reinterpret_cast<const bf16x8*>(&bstage[hf][nt * 32 + l31][0]);
        const bf16x8 bf1 = *reinterpret_cast<const bf16x8*>(&bstage[hf][(nt + 1) * 32 + l31][0]);
        f32x16 acc0 = __builtin_amdgcn_mfma_f32_32x32x16_bf16(afrag, bf0, zero, 0, 0, 0);
        f32x16 acc1 = __builtin_amdgcn_mfma_f32_32x32x16_bf16(afrag, bf1, zero, 0, 0, 0);

        // fwd: per-row running min — v_min3 per reg
#pragma unroll
        for (int r = 0; r < 16; ++r) fwd[r] = fminf(fwd[r], fminf(acc0[r], acc1[r]));

        // bwd: min over this lane's 16 rows, per tile (min3 trees), then LDS merge
        {
            const float t0 = fminf(fminf(acc0[0],  acc0[1]),  acc0[2]);
            const float t1 = fminf(fminf(acc0[3],  acc0[4]),  acc0[5]);
            const float t2 = fminf(fminf(acc0[6],  acc0[7]),  acc0[8]);
            const float t3 = fminf(fminf(acc0[9],  acc0[10]), acc0[11]);
            const float t4 = fminf(fminf(acc0[12], acc0[13]), acc0[14]);
            const float u0 = fminf(fminf(t0, t1), t2);
            const float u1 = fminf(fminf(t3, t4), acc0[15]);
            const float cm = fmaxf(fminf(u0, u1), 0.0f);
            atomicMin(&bwd_lds[nt * 32 + l31], __float_as_uint(cm));
        }
        {
            const float t0 = fminf(fminf(acc1[0],  acc1[1]),  acc1[2]);
            const float t1 = fminf(fminf(acc1[3],  acc1[4]),  acc1[5]);
            const float t2 = fminf(fminf(acc1[6],  acc1[7]),  acc1[8]);
            const float t3 = fminf(fminf(acc1[9],  acc1[10]), acc1[11]);
            const float t4 = fminf(fminf(acc1[12], acc1[13]), acc1[14]);
            const float u0 = fminf(fminf(t0, t1), t2);
            const float u1 = fminf(fminf(t3, t4), acc1[15]);
            const float cm = fmaxf(fminf(u0, u1), 0.0f);
            atomicMin(&bwd_lds[(nt + 1) * 32 + l31], __float_as_uint(cm));
        }
    }

    // fwd: butterfly min across the 32-lane col dimension (halves = distinct rows)
#pragma unroll
    for (int r = 0; r < 16; ++r) {
        float vv = fwd[r];
        vv = fminf(vv, __shfl_xor(vv, 1));
        vv = fminf(vv, __shfl_xor(vv, 2));
        vv = fminf(vv, __shfl_xor(vv, 4));
        vv = fminf(vv, __shfl_xor(vv, 8));
        vv = fminf(vv, __shfl_xor(vv, 16));
        fwd[r] = vv;
    }
    if (l31 == 0) {   // lanes 0 (row-half 0) and 32 (row-half 1)
        float* pf = part_fwd + (((size_t)ns * B) + b) * M + mg * 128 + wave * 32 + hf * 4;
#pragma unroll
        for (int r = 0; r < 16; ++r)
            pf[(r & 3) + 8 * (r >> 2)] = fwd[r];
    }

    __syncthreads();
    {
        float* pb = part_bwd + (((size_t)mg * B) + b) * N + ns * 512;
        pb[tid]       = __uint_as_float(bwd_lds[tid]);
        pb[tid + 256] = __uint_as_float(bwd_lds[tid + 256]);
    }
}

__global__ __launch_bounds__(256) void chamfer_reduce(
    const float* __restrict__ part_fwd, const float* __restrict__ part_bwd,
    float* __restrict__ out)
{
    int idx = blockIdx.x * 256 + threadIdx.x;   // [0, 2*B*M); dir uniform per block
    const int q   = idx & (M - 1); idx >>= 12;
    const int b   = idx & (B - 1); idx >>= 3;
    const int dir = idx;

    float m0 = 3.0e38f, m1 = 3.0e38f, m2 = 3.0e38f, m3 = 3.0e38f;
    if (dir == 0) {
        const float* p = part_fwd + (size_t)b * M + q;
#pragma unroll
        for (int k = 0; k < 8; k += 4) {
            m0 = fminf(m0, p[(size_t)(k + 0) * B * M]);
            m1 = fminf(m1, p[(size_t)(k + 1) * B * M]);
            m2 = fminf(m2, p[(size_t)(k + 2) * B * M]);
            m3 = fminf(m3, p[(size_t)(k + 3) * B * M]);
        }
    } else {
        const float* p = part_bwd + (size_t)b * N + q;
#pragma unroll
        for (int k = 0; k < 32; k += 4) {
            m0 = fminf(m0, p[(size_t)(k + 0) * B * N]);
            m1 = fminf(m1, p[(size_t)(k + 1) * B * N]);
            m2 = fminf(m2, p[(size_t)(k + 2) * B * N]);
            m3 = fminf(m3, p[(size_t)(k + 3) * B * N]);
        }
    }
    const float v = fminf(fminf(m0, m1), fminf(m2, m3));

    float s = sqrtf(fmaxf(v, 0.0f)) * (1.0f / (float)(B * M));  // M==N: one scale
#pragma unroll
    for (int off = 32; off > 0; off >>= 1) s += __shfl_down(s, off);
    __shared__ float partial[4];
    if ((threadIdx.x & 63) == 0) partial[threadIdx.x >> 6] = s;
    __syncthreads();
    if (threadIdx.x == 0) {
        const float tot = partial[0] + partial[1] + partial[2] + partial[3];
        atomicAdd(&out[0], tot);
        atomicAdd(&out[1], tot);
        atomicAdd(&out[2], tot);
    }
}

extern "C" void kernel_launch(void* const* d_in, const int* in_sizes, int n_in,
                              void* d_out, int out_size, void* d_ws, size_t ws_size,
                              hipStream_t stream)
{
    const float* src = (const float*)d_in[0];   // [B,3,M]
    const float* dst = (const float*)d_in[1];   // [B,3,N]
    float* out = (float*)d_out;

    float* pfwd = (float*)d_ws;                           // 1 MB
    float* pbwd = (float*)((char*)d_ws + (4u << 20));     // 4 MB

    hipMemsetAsync(d_out, 0, (size_t)out_size * sizeof(float), stream);

    chamfer_mfma<<<B * 32 * 8, 256, 0, stream>>>(src, dst, pfwd, pbwd);
    chamfer_reduce<<<2 * B * M / 256, 256, 0, stream>>>(pfwd, pbwd, out);
}